// Round 5
// baseline (168.303 us; speedup 1.0000x reference)
//
#include <hip/hip_runtime.h>
#include <math.h>

// B=4, S=4096, D=512, E=64. Fused bf16-MFMA attention, no-max softmax
// (|score·log2e/8| small -> exp2 never overflows; scale folded into Wq/bq).
#define S_ 4096
#define C_SCALE 0.18033688011112042f  // log2(e)/8
#define KSPLIT 8

typedef __attribute__((ext_vector_type(4))) float  floatx4;
typedef __attribute__((ext_vector_type(4))) short  short4_t;
typedef __attribute__((ext_vector_type(8))) short  short8_t;
typedef __attribute__((ext_vector_type(4))) unsigned int uintx4;

__device__ __forceinline__ short f2bf(float f) {  // round half up
  unsigned u = __builtin_bit_cast(unsigned, f);
  u += 0x7FFFu + ((u >> 16) & 1u);
  return (short)(u >> 16);
}
// round-half-up pack: two floats -> two bf16 in one dword
__device__ __forceinline__ unsigned pack2(float lo, float hi) {
  unsigned a = __builtin_bit_cast(unsigned, lo) + 0x8000u;
  unsigned b = __builtin_bit_cast(unsigned, hi) + 0x8000u;
  return __builtin_amdgcn_perm(b, a, 0x07060302u);  // [b.hi16 | a.hi16]
}
// truncating pack (P only: truncation bias cancels in P/sum(P))
__device__ __forceinline__ unsigned packt(float lo, float hi) {
  return __builtin_amdgcn_perm(__builtin_bit_cast(unsigned, hi),
                               __builtin_bit_cast(unsigned, lo), 0x07060302u);
}
__device__ __forceinline__ float bf2f(short s) {
  return __builtin_bit_cast(float, (unsigned)((unsigned short)s) << 16);
}
// async global->LDS DMA, 16B/lane; lds base wave-uniform (HW adds lane*16)
__device__ __forceinline__ void dma16(const void* g, void* l) {
  __builtin_amdgcn_global_load_lds(
      (const __attribute__((address_space(1))) void*)g,
      (__attribute__((address_space(3))) void*)l, 16, 0, 0);
}

// ---------------------------------------------------------------------------
// Kernel 0: W[512][64] -> Wt[m][n=64][k=512] bf16 (C_SCALE folded into Wq).
// ---------------------------------------------------------------------------
__global__ __launch_bounds__(256) void prep_w(const float* __restrict__ Wq,
                                              const float* __restrict__ Wk,
                                              const float* __restrict__ Wv,
                                              short* __restrict__ Wt) {
  __shared__ float T[64 * 65];
  int m = blockIdx.x >> 3, kt = blockIdx.x & 7, tid = threadIdx.x;
  const float* W = (m == 0) ? Wq : (m == 1) ? Wk : Wv;
  float sc = (m == 0) ? C_SCALE : 1.0f;
#pragma unroll
  for (int i = 0; i < 16; i++) {
    int e = i * 256 + tid;
    int k = e >> 6, n = e & 63;
    T[k * 65 + n] = W[(kt * 64 + k) * 64 + n];
  }
  __syncthreads();
#pragma unroll
  for (int i = 0; i < 16; i++) {
    int e = i * 256 + tid;
    int n = e >> 6, k = e & 63;
    Wt[m * 32768 + n * 512 + kt * 64 + k] = f2bf(T[k * 65 + n] * sc);
  }
}

// ---------------------------------------------------------------------------
// Kernel 1: projections. Wave = 16-output-col slice, its full 16x512 W in
// 64 VGPRs (preloaded once; no W staging/DMA). A double-buffered in LDS,
// ONE barrier per kc (next overwrite of a buffer is 2 barriers downstream).
// A-prefetch issued after the barrier so latency hides under the MFMAs.
// grid 768 = (m, 256 x 64-row tiles).
// ---------------------------------------------------------------------------
__global__ __launch_bounds__(256, 3) void proj_kernel(
    const float* __restrict__ qin, const float* __restrict__ kin,
    const float* __restrict__ vin, const float* __restrict__ bq,
    const float* __restrict__ bk, const float* __restrict__ bv,
    const short* __restrict__ Wt, short* __restrict__ Qp,
    short* __restrict__ Kp, short* __restrict__ Vt) {
  __shared__ short A_lds[2][64 * 64];  // bf16 tile dbuf, 8 KB each, swizzled

  int tid = threadIdx.x;
  int m = blockIdx.x >> 8;
  int r0 = (blockIdx.x & 255) * 64;
  int wid = tid >> 6, lane = tid & 63, l15 = lane & 15, quad = lane >> 4;

  const float* in = (m == 0) ? qin : (m == 1) ? kin : vin;
  const short* Wm = Wt + m * 32768;

  // Preload this wave's W-slice: B[k][n] frags for all kc, eh. 64 VGPRs.
  short8_t wf[8][2];
#pragma unroll
  for (int kc = 0; kc < 8; kc++)
#pragma unroll
    for (int eh = 0; eh < 2; eh++)
      wf[kc][eh] = *(const short8_t*)(Wm + (wid * 16 + l15) * 512 + kc * 64 +
                                      eh * 32 + quad * 8);

  // A staging: thread covers rows sr, sr+32, 16B-chunk sc (phys = sc^(sr&7)).
  int sr = tid >> 3, sc = tid & 7;
  int sphys = (sc ^ (sr & 7)) * 8;

  floatx4 ar[4];
  auto loadA = [&](int kc) {
    const float* p = in + (size_t)(r0 + sr) * 512 + kc * 64 + sc * 8;
    ar[0] = *(const floatx4*)p;
    ar[1] = *(const floatx4*)(p + 4);
    const float* p2 = p + 32 * 512;
    ar[2] = *(const floatx4*)p2;
    ar[3] = *(const floatx4*)(p2 + 4);
  };

  floatx4 acc[4];
#pragma unroll
  for (int rt = 0; rt < 4; rt++) acc[rt] = (floatx4){0.f, 0.f, 0.f, 0.f};

  loadA(0);
#pragma unroll
  for (int kc = 0; kc < 8; kc++) {
    uintx4 w0 = {pack2(ar[0][0], ar[0][1]), pack2(ar[0][2], ar[0][3]),
                 pack2(ar[1][0], ar[1][1]), pack2(ar[1][2], ar[1][3])};
    uintx4 w1 = {pack2(ar[2][0], ar[2][1]), pack2(ar[2][2], ar[2][3]),
                 pack2(ar[3][0], ar[3][1]), pack2(ar[3][2], ar[3][3])};
    short* Ab = &A_lds[kc & 1][0];
    *(short8_t*)(Ab + sr * 64 + sphys) = __builtin_bit_cast(short8_t, w0);
    *(short8_t*)(Ab + (sr + 32) * 64 + sphys) = __builtin_bit_cast(short8_t, w1);
    __syncthreads();  // tile visible; prev buffer's readers are done (see note)
    if (kc < 7) loadA(kc + 1);  // latency overlaps MFMAs below
    int akey = l15 & 7;
#pragma unroll
    for (int rt = 0; rt < 4; rt++) {
      int arow = rt * 16 + l15;
#pragma unroll
      for (int eh = 0; eh < 2; eh++) {
        short8_t af = *(const short8_t*)(Ab + arow * 64 + ((eh * 4 + quad) ^ akey) * 8);
        acc[rt] = __builtin_amdgcn_mfma_f32_16x16x32_bf16(af, wf[kc][eh], acc[rt], 0, 0, 0);
      }
    }
  }

  const float* bias = (m == 0) ? bq : (m == 1) ? bk : bv;
  float bsc = (m == 0) ? C_SCALE : 1.0f;
  float bv_ = bias[wid * 16 + l15] * bsc;
  if (m < 2) {
    short* out = (m == 0) ? Qp : Kp;
#pragma unroll
    for (int rt = 0; rt < 4; rt++)
#pragma unroll
      for (int r = 0; r < 4; r++)
        out[(size_t)(r0 + rt * 16 + quad * 4 + r) * 64 + wid * 16 + l15] =
            f2bf(acc[rt][r] + bv_);
  } else {
    int bb = r0 >> 12;
    int s0 = (r0 & 4095);
#pragma unroll
    for (int rt = 0; rt < 4; rt++) {
      short4_t pk = {f2bf(acc[rt][0] + bv_), f2bf(acc[rt][1] + bv_),
                     f2bf(acc[rt][2] + bv_), f2bf(acc[rt][3] + bv_)};
      *(short4_t*)(Vt + (size_t)bb * 262144 + (wid * 16 + l15) * 4096 + s0 +
                   rt * 16 + quad * 4) = pk;
    }
  }
}

// ---------------------------------------------------------------------------
// Kernel 2: flash attention, K-split=8, NO P LDS round-trip.
// QK^T computed as S^T = K·Q^T with PERMUTED A-rows (m -> 8*(m>>2)+(m&3), and
// +4 for the twin tile): the two C-tiles' 8 regs then hold exactly
// j = quad*8 + {0..7} — the K=32 B-operand layout. exp2+pack in regs and feed
// P straight into O^T = V^T·P. K-LDS swizzle key (r&3)|((r>>3&1)<<2) keeps
// the permuted reads conflict-free. grid 512 = (ks, b, 256-q tile).
// ---------------------------------------------------------------------------
__global__ __launch_bounds__(256, 2) void attn_kernel(
    const short* __restrict__ Qp, const short* __restrict__ Kp,
    const short* __restrict__ Vt, short* __restrict__ Po,
    float* __restrict__ Lp) {
  __shared__ short K_lds[2][64 * 64];  // [j][e]
  __shared__ short V_lds[2][64 * 64];  // [e][j]

  int tid = threadIdx.x;
  int ks = blockIdx.x >> 6, b = (blockIdx.x >> 4) & 3, qt = blockIdx.x & 15;
  int wid = tid >> 6, lane = tid & 63, l15 = lane & 15, quad = lane >> 4;

  const short* Qb = Qp + (size_t)b * (S_ * 64);
  const short* Kb = Kp + (size_t)b * (S_ * 64);
  const short* Vb = Vt + (size_t)b * (64 * S_);

  int q0 = qt * 256 + wid * 64;

  // Persistent Q B-fragments (64 q-rows): qf[qs][eh]
  short8_t qf[4][2];
#pragma unroll
  for (int qs = 0; qs < 4; qs++)
#pragma unroll
    for (int h = 0; h < 2; h++)
      qf[qs][h] = *(const short8_t*)(Qb + (q0 + qs * 16 + l15) * 64 + h * 32 + quad * 8);

  floatx4 o[4][4];  // O^T C-tiles: [qs][eb], lane(q=l15, e=eb*16+quad*4+r)
#pragma unroll
  for (int qs = 0; qs < 4; qs++)
#pragma unroll
    for (int eb = 0; eb < 4; eb++) o[qs][eb] = (floatx4){0.f, 0.f, 0.f, 0.f};
  float l_acc[4] = {0.f, 0.f, 0.f, 0.f};
  int ks_base = ks * 512;

  auto stage = [&](int t, int buf) {
    int ks0 = ks_base + t * 64;
#pragma unroll
    for (int j = 0; j < 2; j++) {
      int slot = wid * 128 + j * 64 + lane;
      int r = slot >> 3, c = slot & 7;
      int kk = (r & 3) | (((r >> 3) & 1) << 2);  // K swizzle key
      dma16(Kb + (ks0 + r) * 64 + (c ^ kk) * 8, (void*)&K_lds[buf][(wid * 2 + j) * 512]);
      dma16(Vb + (size_t)r * 4096 + ks0 + (c ^ (r & 7)) * 8,
            (void*)&V_lds[buf][(wid * 2 + j) * 512]);
    }
  };

  stage(0, 0);
  for (int t = 0; t < 8; t++) {
    __syncthreads();  // prev compute done -> other buffer free
    if (t < 7) stage(t + 1, (t + 1) & 1);
    __syncthreads();  // buf[t] ready
    const short* Kt = K_lds[t & 1];
    const short* Vl = V_lds[t & 1];

    int pr = 8 * (l15 >> 2) + (l15 & 3);                   // permuted A-row
    int kkey = (l15 & 3) | (((l15 >> 2) & 1) << 2);        // matches staging key

#pragma unroll
    for (int jg = 0; jg < 2; jg++) {  // 32-j groups
      const short* Kg = Kt + (jg * 32 + pr) * 64;
      short8_t kA0 = *(const short8_t*)(Kg + ((0 + quad) ^ kkey) * 8);
      short8_t kA1 = *(const short8_t*)(Kg + ((4 + quad) ^ kkey) * 8);
      short8_t kA2 = *(const short8_t*)(Kg + 256 + ((0 + quad) ^ kkey) * 8);  // +4 rows
      short8_t kA3 = *(const short8_t*)(Kg + 256 + ((4 + quad) ^ kkey) * 8);
      short8_t vf[4];
#pragma unroll
      for (int eb = 0; eb < 4; eb++)
        vf[eb] = *(const short8_t*)(Vl + (eb * 16 + l15) * 64 +
                                    ((jg * 4 + quad) ^ (l15 & 7)) * 8);
#pragma unroll
      for (int qs = 0; qs < 4; qs++) {
        floatx4 z = (floatx4){0.f, 0.f, 0.f, 0.f};
        floatx4 s0 = __builtin_amdgcn_mfma_f32_16x16x32_bf16(kA0, qf[qs][0], z, 0, 0, 0);
        s0 = __builtin_amdgcn_mfma_f32_16x16x32_bf16(kA1, qf[qs][1], s0, 0, 0, 0);
        floatx4 s1 = __builtin_amdgcn_mfma_f32_16x16x32_bf16(kA2, qf[qs][0], z, 0, 0, 0);
        s1 = __builtin_amdgcn_mfma_f32_16x16x32_bf16(kA3, qf[qs][1], s1, 0, 0, 0);
        // lane reg layout now: s0 -> j = jg*32 + quad*8 + {0..3}, s1 -> +{4..7}
        float e00 = __builtin_amdgcn_exp2f(s0[0]), e01 = __builtin_amdgcn_exp2f(s0[1]);
        float e02 = __builtin_amdgcn_exp2f(s0[2]), e03 = __builtin_amdgcn_exp2f(s0[3]);
        float e10 = __builtin_amdgcn_exp2f(s1[0]), e11 = __builtin_amdgcn_exp2f(s1[1]);
        float e12 = __builtin_amdgcn_exp2f(s1[2]), e13 = __builtin_amdgcn_exp2f(s1[3]);
        l_acc[qs] += ((e00 + e01) + (e02 + e03)) + ((e10 + e11) + (e12 + e13));
        uintx4 bp = {packt(e00, e01), packt(e02, e03),
                     packt(e10, e11), packt(e12, e13)};
        short8_t pB = __builtin_bit_cast(short8_t, bp);  // exact K=32 B-operand
#pragma unroll
        for (int eb = 0; eb < 4; eb++)
          o[qs][eb] = __builtin_amdgcn_mfma_f32_16x16x32_bf16(vf[eb], pB, o[qs][eb], 0, 0, 0);
      }
    }
  }

  // Epilogue: l reduced across quads; store un-normalized partials.
#pragma unroll
  for (int qs = 0; qs < 4; qs++) {
    float l = l_acc[qs];
    l += __shfl_xor(l, 16, 64);
    l += __shfl_xor(l, 32, 64);
    int grow = b * 4096 + q0 + qs * 16 + l15;
    short* Pb = Po + ((size_t)ks * 16384 + grow) * 64;
#pragma unroll
    for (int eb = 0; eb < 4; eb++) {
      short4_t pk = {f2bf(o[qs][eb][0]), f2bf(o[qs][eb][1]),
                     f2bf(o[qs][eb][2]), f2bf(o[qs][eb][3])};
      *(short4_t*)(Pb + eb * 16 + quad * 4) = pk;
    }
    if (quad == 0) Lp[ks * 16384 + grow] = l;
  }
}

// ---------------------------------------------------------------------------
// Kernel 3: combine bf16 partials: out = (sum_ks o) / (sum_ks l).
// ---------------------------------------------------------------------------
__global__ __launch_bounds__(256) void combine_kernel(
    const short* __restrict__ Po, const float* __restrict__ Lp,
    float* __restrict__ out) {
  int gid = blockIdx.x * 256 + threadIdx.x;
  int grow = gid >> 3, e0 = (gid & 7) * 8;
  float s[8];
#pragma unroll
  for (int i = 0; i < 8; i++) s[i] = 0.f;
  float l = 0.f;
#pragma unroll
  for (int ks = 0; ks < KSPLIT; ks++) {
    short8_t p = *(const short8_t*)(Po + ((size_t)ks * 16384 + grow) * 64 + e0);
#pragma unroll
    for (int i = 0; i < 8; i++) s[i] += bf2f(p[i]);
    l += Lp[ks * 16384 + grow];
  }
  float inv = 1.0f / l;
  floatx4 o0 = {s[0] * inv, s[1] * inv, s[2] * inv, s[3] * inv};
  floatx4 o1 = {s[4] * inv, s[5] * inv, s[6] * inv, s[7] * inv};
  *(floatx4*)(out + (size_t)grow * 64 + e0) = o0;
  *(floatx4*)(out + (size_t)grow * 64 + e0 + 4) = o1;
}

// ---------------------------------------------------------------------------
extern "C" void kernel_launch(void* const* d_in, const int* in_sizes, int n_in,
                              void* d_out, int out_size, void* d_ws, size_t ws_size,
                              hipStream_t stream) {
  const float* q = (const float*)d_in[0];
  const float* k = (const float*)d_in[1];
  const float* v = (const float*)d_in[2];
  const float* Wq = (const float*)d_in[3];
  const float* bq = (const float*)d_in[4];
  const float* Wk = (const float*)d_in[5];
  const float* bk = (const float*)d_in[6];
  const float* Wv = (const float*)d_in[7];
  const float* bv = (const float*)d_in[8];

  // ws (~28 MB): Qp 0..2M | Kp 2..4M | Vt 4..6M | Wt 6..8M |
  //              Po(bf16) 8M..24.8M | Lp 26M..26.5M
  char* ws = (char*)d_ws;
  short* Qp = (short*)(ws);
  short* Kp = (short*)(ws + (1u << 21));
  short* Vt = (short*)(ws + (2u << 21));
  short* Wt = (short*)(ws + (3u << 21));
  short* Po = (short*)(ws + (4u << 21));
  float* Lp = (float*)(ws + (13u << 21));

  prep_w<<<24, 256, 0, stream>>>(Wq, Wk, Wv, Wt);
  proj_kernel<<<768, 256, 0, stream>>>(q, k, v, bq, bk, bv, Wt, Qp, Kp, Vt);
  attn_kernel<<<512, 256, 0, stream>>>(Qp, Kp, Vt, Po, Lp);
  combine_kernel<<<512, 256, 0, stream>>>(Po, Lp, (float*)d_out);
}

// Round 6
// 168.272 us; speedup vs baseline: 1.0002x; 1.0002x over previous
//
#include <hip/hip_runtime.h>
#include <math.h>

// B=4, S=4096, D=512, E=64. Fused bf16-MFMA attention, no-max softmax
// (|score·log2e/8| small -> exp2 never overflows; scale folded into Wq/bq).
#define S_ 4096
#define C_SCALE 0.18033688011112042f  // log2(e)/8
#define KSPLIT 8

typedef __attribute__((ext_vector_type(4))) float  floatx4;
typedef __attribute__((ext_vector_type(4))) short  short4_t;
typedef __attribute__((ext_vector_type(8))) short  short8_t;
typedef __attribute__((ext_vector_type(4))) unsigned int uintx4;

__device__ __forceinline__ short f2bf(float f) {  // round half up
  unsigned u = __builtin_bit_cast(unsigned, f);
  u += 0x7FFFu + ((u >> 16) & 1u);
  return (short)(u >> 16);
}
// round-half-up pack: two floats -> two bf16 in one dword
__device__ __forceinline__ unsigned pack2(float lo, float hi) {
  unsigned a = __builtin_bit_cast(unsigned, lo) + 0x8000u;
  unsigned b = __builtin_bit_cast(unsigned, hi) + 0x8000u;
  return __builtin_amdgcn_perm(b, a, 0x07060302u);  // [b.hi16 | a.hi16]
}
// truncating pack (P only: truncation bias cancels in P/sum(P))
__device__ __forceinline__ unsigned packt(float lo, float hi) {
  return __builtin_amdgcn_perm(__builtin_bit_cast(unsigned, hi),
                               __builtin_bit_cast(unsigned, lo), 0x07060302u);
}
__device__ __forceinline__ float bf2f(short s) {
  return __builtin_bit_cast(float, (unsigned)((unsigned short)s) << 16);
}

// ---------------------------------------------------------------------------
// Kernel 0: W[512][64] -> Wt[m][n=64][k=512] bf16 (C_SCALE folded into Wq).
// ---------------------------------------------------------------------------
__global__ __launch_bounds__(256) void prep_w(const float* __restrict__ Wq,
                                              const float* __restrict__ Wk,
                                              const float* __restrict__ Wv,
                                              short* __restrict__ Wt) {
  __shared__ float T[64 * 65];
  int m = blockIdx.x >> 3, kt = blockIdx.x & 7, tid = threadIdx.x;
  const float* W = (m == 0) ? Wq : (m == 1) ? Wk : Wv;
  float sc = (m == 0) ? C_SCALE : 1.0f;
#pragma unroll
  for (int i = 0; i < 16; i++) {
    int e = i * 256 + tid;
    int k = e >> 6, n = e & 63;
    T[k * 65 + n] = W[(kt * 64 + k) * 64 + n];
  }
  __syncthreads();
#pragma unroll
  for (int i = 0; i < 16; i++) {
    int e = i * 256 + tid;
    int n = e >> 6, k = e & 63;
    Wt[m * 32768 + n * 512 + kt * 64 + k] = f2bf(T[k * 65 + n] * sc);
  }
}

// ---------------------------------------------------------------------------
// Kernel 1: projections (unchanged from R5). Wave = 16-output-col slice with
// its 16x512 W-slice in 64 VGPRs; A double-buffered in LDS, ONE barrier/kc;
// A-prefetch after the barrier hides under the MFMAs.
// ---------------------------------------------------------------------------
__global__ __launch_bounds__(256, 3) void proj_kernel(
    const float* __restrict__ qin, const float* __restrict__ kin,
    const float* __restrict__ vin, const float* __restrict__ bq,
    const float* __restrict__ bk, const float* __restrict__ bv,
    const short* __restrict__ Wt, short* __restrict__ Qp,
    short* __restrict__ Kp, short* __restrict__ Vt) {
  __shared__ short A_lds[2][64 * 64];  // bf16 tile dbuf, 8 KB each, swizzled

  int tid = threadIdx.x;
  int m = blockIdx.x >> 8;
  int r0 = (blockIdx.x & 255) * 64;
  int wid = tid >> 6, lane = tid & 63, l15 = lane & 15, quad = lane >> 4;

  const float* in = (m == 0) ? qin : (m == 1) ? kin : vin;
  const short* Wm = Wt + m * 32768;

  short8_t wf[8][2];
#pragma unroll
  for (int kc = 0; kc < 8; kc++)
#pragma unroll
    for (int eh = 0; eh < 2; eh++)
      wf[kc][eh] = *(const short8_t*)(Wm + (wid * 16 + l15) * 512 + kc * 64 +
                                      eh * 32 + quad * 8);

  int sr = tid >> 3, sc = tid & 7;
  int sphys = (sc ^ (sr & 7)) * 8;

  floatx4 ar[4];
  auto loadA = [&](int kc) {
    const float* p = in + (size_t)(r0 + sr) * 512 + kc * 64 + sc * 8;
    ar[0] = *(const floatx4*)p;
    ar[1] = *(const floatx4*)(p + 4);
    const float* p2 = p + 32 * 512;
    ar[2] = *(const floatx4*)p2;
    ar[3] = *(const floatx4*)(p2 + 4);
  };

  floatx4 acc[4];
#pragma unroll
  for (int rt = 0; rt < 4; rt++) acc[rt] = (floatx4){0.f, 0.f, 0.f, 0.f};

  loadA(0);
#pragma unroll
  for (int kc = 0; kc < 8; kc++) {
    uintx4 w0 = {pack2(ar[0][0], ar[0][1]), pack2(ar[0][2], ar[0][3]),
                 pack2(ar[1][0], ar[1][1]), pack2(ar[1][2], ar[1][3])};
    uintx4 w1 = {pack2(ar[2][0], ar[2][1]), pack2(ar[2][2], ar[2][3]),
                 pack2(ar[3][0], ar[3][1]), pack2(ar[3][2], ar[3][3])};
    short* Ab = &A_lds[kc & 1][0];
    *(short8_t*)(Ab + sr * 64 + sphys) = __builtin_bit_cast(short8_t, w0);
    *(short8_t*)(Ab + (sr + 32) * 64 + sphys) = __builtin_bit_cast(short8_t, w1);
    __syncthreads();
    if (kc < 7) loadA(kc + 1);
    int akey = l15 & 7;
#pragma unroll
    for (int rt = 0; rt < 4; rt++) {
      int arow = rt * 16 + l15;
#pragma unroll
      for (int eh = 0; eh < 2; eh++) {
        short8_t af = *(const short8_t*)(Ab + arow * 64 + ((eh * 4 + quad) ^ akey) * 8);
        acc[rt] = __builtin_amdgcn_mfma_f32_16x16x32_bf16(af, wf[kc][eh], acc[rt], 0, 0, 0);
      }
    }
  }

  const float* bias = (m == 0) ? bq : (m == 1) ? bk : bv;
  float bsc = (m == 0) ? C_SCALE : 1.0f;
  float bv_ = bias[wid * 16 + l15] * bsc;
  if (m < 2) {
    short* out = (m == 0) ? Qp : Kp;
#pragma unroll
    for (int rt = 0; rt < 4; rt++)
#pragma unroll
      for (int r = 0; r < 4; r++)
        out[(size_t)(r0 + rt * 16 + quad * 4 + r) * 64 + wid * 16 + l15] =
            f2bf(acc[rt][r] + bv_);
  } else {
    int bb = r0 >> 12;
    int s0 = (r0 & 4095);
#pragma unroll
    for (int rt = 0; rt < 4; rt++) {
      short4_t pk = {f2bf(acc[rt][0] + bv_), f2bf(acc[rt][1] + bv_),
                     f2bf(acc[rt][2] + bv_), f2bf(acc[rt][3] + bv_)};
      *(short4_t*)(Vt + (size_t)bb * 262144 + (wid * 16 + l15) * 4096 + s0 +
                   rt * 16 + quad * 4) = pk;
    }
  }
}

// ---------------------------------------------------------------------------
// Kernel 2: flash attention, K-split=8. SINGLE-BARRIER pipelined staging:
//   loadKV(0); for t { writeKV(t); barrier; loadKV(t+1); compute(t); }
// Global loads for t+1 fly during compute(t); barrier drain residual ~0.
// Register staging (ds_write) avoids the DMA-vs-ds_read alias hazard.
// Permuted-K QK^T (R5, verified): P lands directly in PV B-operand layout.
// l via ones-A-row MFMA on the packed pB (consistent with truncated P).
// ---------------------------------------------------------------------------
__global__ __launch_bounds__(256, 2) void attn_kernel(
    const short* __restrict__ Qp, const short* __restrict__ Kp,
    const short* __restrict__ Vt, short* __restrict__ Po,
    float* __restrict__ Lp) {
  __shared__ short K_lds[2][64 * 64];  // [j][e], swizzled
  __shared__ short V_lds[2][64 * 64];  // [e][j], swizzled

  int tid = threadIdx.x;
  int ks = blockIdx.x >> 6, b = (blockIdx.x >> 4) & 3, qt = blockIdx.x & 15;
  int wid = tid >> 6, lane = tid & 63, l15 = lane & 15, quad = lane >> 4;

  const short* Qb = Qp + (size_t)b * (S_ * 64);
  const short* Kb = Kp + (size_t)b * (S_ * 64);
  const short* Vb = Vt + (size_t)b * (64 * S_);

  int q0 = qt * 256 + wid * 64;

  // Persistent Q B-fragments (64 q-rows)
  short8_t qf[4][2];
#pragma unroll
  for (int qs = 0; qs < 4; qs++)
#pragma unroll
    for (int h = 0; h < 2; h++)
      qf[qs][h] = *(const short8_t*)(Qb + (q0 + qs * 16 + l15) * 64 + h * 32 + quad * 8);

  floatx4 o[4][4];   // O^T tiles: lane(q=l15, e=eb*16+quad*4+r)
  floatx4 ol[4];     // l accumulator via ones-row MFMA (all quads identical)
#pragma unroll
  for (int qs = 0; qs < 4; qs++) {
    ol[qs] = (floatx4){0.f, 0.f, 0.f, 0.f};
#pragma unroll
    for (int eb = 0; eb < 4; eb++) o[qs][eb] = (floatx4){0.f, 0.f, 0.f, 0.f};
  }

  short8_t ones;
#pragma unroll
  for (int i = 0; i < 8; i++) ones[i] = (short)0x3F80;  // 1.0 bf16

  // staging: thread covers rows sr,sr+32 (chunk sc) of K and V tiles
  int sr = tid >> 3, sc = tid & 7;
  int kk = (sr & 3) | (((sr >> 3) & 1) << 2);  // K swizzle key (rows sr,sr+32 equal)
  int vk = sr & 7;                             // V swizzle key
  short8_t kr0, kr1, vr0, vr1;
  int ks_base = ks * 512;

  auto loadKV = [&](int t) {
    int ks0 = ks_base + t * 64;
    kr0 = *(const short8_t*)(Kb + (ks0 + sr) * 64 + sc * 8);
    kr1 = *(const short8_t*)(Kb + (ks0 + sr + 32) * 64 + sc * 8);
    vr0 = *(const short8_t*)(Vb + (size_t)sr * 4096 + ks0 + sc * 8);
    vr1 = *(const short8_t*)(Vb + (size_t)(sr + 32) * 4096 + ks0 + sc * 8);
  };
  auto writeKV = [&](int buf) {
    *(short8_t*)(&K_lds[buf][sr * 64 + ((sc ^ kk) * 8)]) = kr0;
    *(short8_t*)(&K_lds[buf][(sr + 32) * 64 + ((sc ^ kk) * 8)]) = kr1;
    *(short8_t*)(&V_lds[buf][sr * 64 + ((sc ^ vk) * 8)]) = vr0;
    *(short8_t*)(&V_lds[buf][(sr + 32) * 64 + ((sc ^ vk) * 8)]) = vr1;
  };

  int pr = 8 * (l15 >> 2) + (l15 & 3);             // permuted A-row
  int kkey = (l15 & 3) | (((l15 >> 2) & 1) << 2);  // matches K staging key
  int vkey = l15 & 7;

  loadKV(0);
#pragma unroll
  for (int t = 0; t < 8; t++) {
    writeKV(t & 1);       // overwrites buffer last read at t-2 (barrier t-1 separates)
    __syncthreads();      // orders writes before reads; drains loads from iter t-1
    if (t < 7) loadKV(t + 1);  // flies during compute below
    const short* Kt = &K_lds[t & 1][0];
    const short* Vl = &V_lds[t & 1][0];

#pragma unroll
    for (int jg = 0; jg < 2; jg++) {  // 32-j groups
      const short* Kg = Kt + (jg * 32 + pr) * 64;
      short8_t kA0 = *(const short8_t*)(Kg + ((0 + quad) ^ kkey) * 8);
      short8_t kA1 = *(const short8_t*)(Kg + ((4 + quad) ^ kkey) * 8);
      short8_t kA2 = *(const short8_t*)(Kg + 256 + ((0 + quad) ^ kkey) * 8);
      short8_t kA3 = *(const short8_t*)(Kg + 256 + ((4 + quad) ^ kkey) * 8);
      short8_t vf[4];
#pragma unroll
      for (int eb = 0; eb < 4; eb++)
        vf[eb] = *(const short8_t*)(Vl + (eb * 16 + l15) * 64 +
                                    ((jg * 4 + quad) ^ vkey) * 8);
#pragma unroll
      for (int qs = 0; qs < 4; qs++) {
        floatx4 z = (floatx4){0.f, 0.f, 0.f, 0.f};
        floatx4 s0 = __builtin_amdgcn_mfma_f32_16x16x32_bf16(kA0, qf[qs][0], z, 0, 0, 0);
        s0 = __builtin_amdgcn_mfma_f32_16x16x32_bf16(kA1, qf[qs][1], s0, 0, 0, 0);
        floatx4 s1 = __builtin_amdgcn_mfma_f32_16x16x32_bf16(kA2, qf[qs][0], z, 0, 0, 0);
        s1 = __builtin_amdgcn_mfma_f32_16x16x32_bf16(kA3, qf[qs][1], s1, 0, 0, 0);
        // lane regs: s0 -> j = jg*32 + quad*8 + {0..3}, s1 -> +{4..7}
        float e00 = __builtin_amdgcn_exp2f(s0[0]), e01 = __builtin_amdgcn_exp2f(s0[1]);
        float e02 = __builtin_amdgcn_exp2f(s0[2]), e03 = __builtin_amdgcn_exp2f(s0[3]);
        float e10 = __builtin_amdgcn_exp2f(s1[0]), e11 = __builtin_amdgcn_exp2f(s1[1]);
        float e12 = __builtin_amdgcn_exp2f(s1[2]), e13 = __builtin_amdgcn_exp2f(s1[3]);
        uintx4 bp = {packt(e00, e01), packt(e02, e03),
                     packt(e10, e11), packt(e12, e13)};
        short8_t pB = __builtin_bit_cast(short8_t, bp);  // exact K=32 B-operand
#pragma unroll
        for (int eb = 0; eb < 4; eb++)
          o[qs][eb] = __builtin_amdgcn_mfma_f32_16x16x32_bf16(vf[eb], pB, o[qs][eb], 0, 0, 0);
        ol[qs] = __builtin_amdgcn_mfma_f32_16x16x32_bf16(ones, pB, ol[qs], 0, 0, 0);
      }
    }
  }

  // Epilogue: every lane already holds l for its q (=l15) in ol[qs][*].
#pragma unroll
  for (int qs = 0; qs < 4; qs++) {
    int grow = b * 4096 + q0 + qs * 16 + l15;
    short* Pb = Po + ((size_t)ks * 16384 + grow) * 64;
#pragma unroll
    for (int eb = 0; eb < 4; eb++) {
      short4_t pk = {f2bf(o[qs][eb][0]), f2bf(o[qs][eb][1]),
                     f2bf(o[qs][eb][2]), f2bf(o[qs][eb][3])};
      *(short4_t*)(Pb + eb * 16 + quad * 4) = pk;
    }
    if (quad == 0) Lp[ks * 16384 + grow] = ol[qs][0];
  }
}

// ---------------------------------------------------------------------------
// Kernel 3: combine bf16 partials: out = (sum_ks o) / (sum_ks l).
// ---------------------------------------------------------------------------
__global__ __launch_bounds__(256) void combine_kernel(
    const short* __restrict__ Po, const float* __restrict__ Lp,
    float* __restrict__ out) {
  int gid = blockIdx.x * 256 + threadIdx.x;
  int grow = gid >> 3, e0 = (gid & 7) * 8;
  float s[8];
#pragma unroll
  for (int i = 0; i < 8; i++) s[i] = 0.f;
  float l = 0.f;
#pragma unroll
  for (int ks = 0; ks < KSPLIT; ks++) {
    short8_t p = *(const short8_t*)(Po + ((size_t)ks * 16384 + grow) * 64 + e0);
#pragma unroll
    for (int i = 0; i < 8; i++) s[i] += bf2f(p[i]);
    l += Lp[ks * 16384 + grow];
  }
  float inv = 1.0f / l;
  floatx4 o0 = {s[0] * inv, s[1] * inv, s[2] * inv, s[3] * inv};
  floatx4 o1 = {s[4] * inv, s[5] * inv, s[6] * inv, s[7] * inv};
  *(floatx4*)(out + (size_t)grow * 64 + e0) = o0;
  *(floatx4*)(out + (size_t)grow * 64 + e0 + 4) = o1;
}

// ---------------------------------------------------------------------------
extern "C" void kernel_launch(void* const* d_in, const int* in_sizes, int n_in,
                              void* d_out, int out_size, void* d_ws, size_t ws_size,
                              hipStream_t stream) {
  const float* q = (const float*)d_in[0];
  const float* k = (const float*)d_in[1];
  const float* v = (const float*)d_in[2];
  const float* Wq = (const float*)d_in[3];
  const float* bq = (const float*)d_in[4];
  const float* Wk = (const float*)d_in[5];
  const float* bk = (const float*)d_in[6];
  const float* Wv = (const float*)d_in[7];
  const float* bv = (const float*)d_in[8];

  // ws (~28 MB): Qp 0..2M | Kp 2..4M | Vt 4..6M | Wt 6..8M |
  //              Po(bf16) 8M..24.8M | Lp 26M..26.5M
  char* ws = (char*)d_ws;
  short* Qp = (short*)(ws);
  short* Kp = (short*)(ws + (1u << 21));
  short* Vt = (short*)(ws + (2u << 21));
  short* Wt = (short*)(ws + (3u << 21));
  short* Po = (short*)(ws + (4u << 21));
  float* Lp = (float*)(ws + (13u << 21));

  prep_w<<<24, 256, 0, stream>>>(Wq, Wk, Wv, Wt);
  proj_kernel<<<768, 256, 0, stream>>>(q, k, v, bq, bk, bv, Wt, Qp, Kp, Vt);
  attn_kernel<<<512, 256, 0, stream>>>(Qp, Kp, Vt, Po, Lp);
  combine_kernel<<<512, 256, 0, stream>>>(Po, Lp, (float*)d_out);
}